// Round 14
// baseline (260.130 us; speedup 1.0000x reference)
//
#include <hip/hip_runtime.h>

#define NN 8192      // nodes
#define NE 262144    // edges
#define DIM 128
#define BCAP 128     // bucket capacity (deg ~ Poisson(32); P(deg>128) ~ 0)

typedef float f32x4 __attribute__((ext_vector_type(4)));
typedef float f32x2 __attribute__((ext_vector_type(2)));

__device__ __forceinline__ float4 f4fma(float s, float4 w, float4 acc) {
    acc.x = fmaf(s, w.x, acc.x);
    acc.y = fmaf(s, w.y, acc.y);
    acc.z = fmaf(s, w.z, acc.z);
    acc.w = fmaf(s, w.w, acc.w);
    return acc;
}
__device__ __forceinline__ float f4dot(float4 a, float4 b) {
    return fmaf(a.x, b.x, fmaf(a.y, b.y, fmaf(a.z, b.z, a.w * b.w)));
}

// ---------------- K1: zero cnt ----------------
__global__ __launch_bounds__(256) void zero_kernel(int* __restrict__ cnt) {
    cnt[blockIdx.x * 256 + threadIdx.x] = 0;
}

// ---------------- K2: fused [gemm_pre_raw (blk 0-255)] | [scatter (blk 256-1279)] | [uv (blk 1280)] ----------------
__global__ __launch_bounds__(256) void fused_pre(const float* __restrict__ X,
                                                 const float* __restrict__ W,
                                                 float* __restrict__ G,
                                                 const int* __restrict__ src,
                                                 const int* __restrict__ dst,
                                                 int* __restrict__ cnt,
                                                 int* __restrict__ bucket,
                                                 const float* __restrict__ Wout,
                                                 const float* __restrict__ bout,
                                                 const float* __restrict__ we,
                                                 const float* __restrict__ bedge,
                                                 float* __restrict__ u,
                                                 float* __restrict__ v,
                                                 float* __restrict__ beta) {
    __shared__ float4 Wl[128 * 32];  // 64KB (gemm branch only)
    __shared__ float4 Xl[32 * 32];   // 16KB (gemm); overlaid as red[] by uv branch
    int tid = threadIdx.x;
    int bid = blockIdx.x;

    if (bid < 256) {
        // ---- raw GEMM: G1[r] = (x @ W1)[r] (dinv commuted into gather) ----
        int rbase = bid * 32;
        const float4* W4 = (const float4*)W;
#pragma unroll
        for (int i = 0; i < 16; ++i) Wl[i * 256 + tid] = W4[i * 256 + tid];
        const float4* X4 = (const float4*)(X + rbase * DIM);
#pragma unroll
        for (int i = 0; i < 4; ++i) Xl[i * 256 + tid] = X4[i * 256 + tid];
        __syncthreads();

        int tx = tid & 31;
        int ty = tid >> 5;
        float4 acc[4];
#pragma unroll
        for (int i = 0; i < 4; ++i) acc[i] = make_float4(0.f, 0.f, 0.f, 0.f);

        for (int k4 = 0; k4 < 32; ++k4) {
            float4 w0 = Wl[(k4 * 4 + 0) * 32 + tx];
            float4 w1 = Wl[(k4 * 4 + 1) * 32 + tx];
            float4 w2 = Wl[(k4 * 4 + 2) * 32 + tx];
            float4 w3 = Wl[(k4 * 4 + 3) * 32 + tx];
#pragma unroll
            for (int i = 0; i < 4; ++i) {
                float4 xv = Xl[(ty * 4 + i) * 32 + k4];
                acc[i] = f4fma(xv.x, w0, acc[i]);
                acc[i] = f4fma(xv.y, w1, acc[i]);
                acc[i] = f4fma(xv.z, w2, acc[i]);
                acc[i] = f4fma(xv.w, w3, acc[i]);
            }
        }
        float4* G4 = (float4*)G;
#pragma unroll
        for (int i = 0; i < 4; ++i) {
            int r = rbase + ty * 4 + i;
            G4[r * 32 + tx] = acc[i];   // plain store: table stays cacheable
        }
        return;
    }
    if (bid < 1280) {
        // ---- scatter edges into buckets; cnt ends as indegree ----
        int e = (bid - 256) * 256 + tid;
        int d = dst[e];
        int p = atomicAdd(&cnt[d], 1);
        if (p < BCAP) bucket[(d << 7) + p] = src[e];
        return;
    }
    // ---- block 1280: u/v/beta ----
    float* red = (float*)Xl;
    int k = tid;
    if (k < DIM) {
        const float4* W4o = (const float4*)(Wout + (k << 7));
        const float4* we4 = (const float4*)we;
        float su = 0.f, sv = 0.f;
#pragma unroll
        for (int j = 0; j < 32; ++j) {
            float4 w = W4o[j];
            su += f4dot(w, we4[j]);
            sv += f4dot(w, we4[32 + j]);
        }
        u[k] = su;
        v[k] = sv;
    }
    red[k] = (k < DIM) ? bout[k] * we[k] : 0.f;
    __syncthreads();
    for (int off = 128; off >= 1; off >>= 1) {
        if (k < off) red[k] += red[k + off];
        __syncthreads();
    }
    float b0 = red[0];
    __syncthreads();
    red[k] = (k < DIM) ? bout[k] * we[DIM + k] : 0.f;
    __syncthreads();
    for (int off = 128; off >= 1; off >>= 1) {
        if (k < off) red[k] += red[k + off];
        __syncthreads();
    }
    if (k == 0) {
        beta[0] = b0 + bedge[0];
        beta[1] = red[0];
    }
}

// ---------------- F2: gather(G1raw, per-edge dinv) + S2 = dv*relu(dv*y + b1) ----------------
__global__ __launch_bounds__(256) void gather_scale(const float* __restrict__ G1,
                                                    const int* __restrict__ cnt,
                                                    const int* __restrict__ bucket,
                                                    const float* __restrict__ b1,
                                                    f32x2* __restrict__ S2) {
    int node = blockIdx.x * 4 + (threadIdx.x >> 6);
    int lane = threadIdx.x & 63;
    const float2* G12 = (const float2*)G1;

    int degree = cnt[node];
    float dv = rsqrtf((float)(degree + 1));
    int deg = min(degree, BCAP);
    int i0 = __builtin_nontemporal_load(bucket + (node << 7) + lane);
    int i1 = __builtin_nontemporal_load(bucket + (node << 7) + 64 + lane);

    float2 selfv = G12[node * 64 + lane];
    float ax = selfv.x * dv, ay = selfv.y * dv;   // self: src dinv = own dv
    float px[8], py[8];
#pragma unroll
    for (int k = 0; k < 8; ++k) { px[k] = 0.f; py[k] = 0.f; }

    int d8 = deg & ~7;
    for (int e = 0; e < d8; e += 8) {
        int s[8];
#pragma unroll
        for (int k = 0; k < 8; ++k) s[k] = __shfl((e + k) >= 64 ? i1 : i0, (e + k) & 63);
#pragma unroll
        for (int k = 0; k < 8; ++k) {
            int ck = cnt[s[k]];
            float2 t = G12[s[k] * 64 + lane];
            float w = rsqrtf((float)(ck + 1));
            px[k] = fmaf(t.x, w, px[k]);
            py[k] = fmaf(t.y, w, py[k]);
        }
    }
    for (int e = d8; e < deg; ++e) {
        int s = __shfl(e >= 64 ? i1 : i0, e & 63);
        int ck = cnt[s];
        float2 t = G12[s * 64 + lane];
        float w = rsqrtf((float)(ck + 1));
        ax = fmaf(t.x, w, ax);
        ay = fmaf(t.y, w, ay);
    }
    float yx = ax + ((px[0] + px[1]) + (px[2] + px[3])) + ((px[4] + px[5]) + (px[6] + px[7]));
    float yy = ay + ((py[0] + py[1]) + (py[2] + py[3])) + ((py[4] + py[5]) + (py[6] + py[7]));

    const float2* B2 = (const float2*)b1;
    float2 bb = B2[lane];
    f32x2 o;
    o.x = fmaxf(fmaf(yx, dv, bb.x), 0.f) * dv;
    o.y = fmaxf(fmaf(yy, dv, bb.y), 0.f) * dv;
    __builtin_nontemporal_store(o, S2 + node * 64 + lane);
}

// ---------------- F3: G2 = S2 @ W2 (raw), plain store ----------------
__global__ __launch_bounds__(256) void gemm_mid(const float* __restrict__ X,
                                                const float* __restrict__ W,
                                                float* __restrict__ G) {
    __shared__ float4 Wl[128 * 32];
    __shared__ float4 Xl[32 * 32];
    int tid = threadIdx.x;
    int rbase = blockIdx.x * 32;

    const float4* W4 = (const float4*)W;
#pragma unroll
    for (int i = 0; i < 16; ++i) Wl[i * 256 + tid] = W4[i * 256 + tid];
    const float4* X4 = (const float4*)(X + rbase * DIM);
#pragma unroll
    for (int i = 0; i < 4; ++i) Xl[i * 256 + tid] = X4[i * 256 + tid];
    __syncthreads();

    int tx = tid & 31;
    int ty = tid >> 5;
    float4 acc[4];
#pragma unroll
    for (int i = 0; i < 4; ++i) acc[i] = make_float4(0.f, 0.f, 0.f, 0.f);

    for (int k4 = 0; k4 < 32; ++k4) {
        float4 w0 = Wl[(k4 * 4 + 0) * 32 + tx];
        float4 w1 = Wl[(k4 * 4 + 1) * 32 + tx];
        float4 w2 = Wl[(k4 * 4 + 2) * 32 + tx];
        float4 w3 = Wl[(k4 * 4 + 3) * 32 + tx];
#pragma unroll
        for (int i = 0; i < 4; ++i) {
            float4 xv = Xl[(ty * 4 + i) * 32 + k4];
            acc[i] = f4fma(xv.x, w0, acc[i]);
            acc[i] = f4fma(xv.y, w1, acc[i]);
            acc[i] = f4fma(xv.z, w2, acc[i]);
            acc[i] = f4fma(xv.w, w3, acc[i]);
        }
    }

    float4* G4 = (float4*)G;
#pragma unroll
    for (int i = 0; i < 4; ++i) {
        int r = rbase + ty * 4 + i;
        G4[r * 32 + tx] = acc[i];
    }
}

// ---------------- F4: gather(G2) + head -> a, c (ILP-8) ----------------
__global__ __launch_bounds__(256) void agg_head(const float* __restrict__ G2,
                                                const int* __restrict__ cnt,
                                                const int* __restrict__ bucket,
                                                const float* __restrict__ b2,
                                                const float* __restrict__ u,
                                                const float* __restrict__ v,
                                                const float* __restrict__ beta,
                                                float* __restrict__ a,
                                                float* __restrict__ c) {
    int node = blockIdx.x * 4 + (threadIdx.x >> 6);
    int lane = threadIdx.x & 63;
    const float2* G22 = (const float2*)G2;

    int degree = cnt[node];
    float dv = rsqrtf((float)(degree + 1));
    int deg = min(degree, BCAP);
    int i0 = __builtin_nontemporal_load(bucket + (node << 7) + lane);
    int i1 = __builtin_nontemporal_load(bucket + (node << 7) + 64 + lane);

    float2 selfv = G22[node * 64 + lane];
    float ax = selfv.x, ay = selfv.y;
    float px[8], py[8];
#pragma unroll
    for (int k = 0; k < 8; ++k) { px[k] = 0.f; py[k] = 0.f; }

    int d8 = deg & ~7;
    for (int e = 0; e < d8; e += 8) {
        int s[8];
#pragma unroll
        for (int k = 0; k < 8; ++k) s[k] = __shfl((e + k) >= 64 ? i1 : i0, (e + k) & 63);
#pragma unroll
        for (int k = 0; k < 8; ++k) {
            float2 t = G22[s[k] * 64 + lane];
            px[k] += t.x;
            py[k] += t.y;
        }
    }
    for (int e = d8; e < deg; ++e) {
        int s = __shfl(e >= 64 ? i1 : i0, e & 63);
        float2 t = G22[s * 64 + lane];
        ax += t.x;
        ay += t.y;
    }
    float yx = ax + ((px[0] + px[1]) + (px[2] + px[3])) + ((px[4] + px[5]) + (px[6] + px[7]));
    float yy = ay + ((py[0] + py[1]) + (py[2] + py[3])) + ((py[4] + py[5]) + (py[6] + py[7]));

    const float2* B2 = (const float2*)b2;
    float2 bb = B2[lane];
    float h0 = fmaxf(fmaf(yx, dv, bb.x), 0.f);
    float h1 = fmaxf(fmaf(yy, dv, bb.y), 0.f);

    float2 uu = ((const float2*)u)[lane];
    float2 vv = ((const float2*)v)[lane];
    float pa = h0 * uu.x + h1 * uu.y;
    float pc = h0 * vv.x + h1 * vv.y;
#pragma unroll
    for (int off = 32; off >= 1; off >>= 1) {
        pa += __shfl_xor(pa, off);
        pc += __shfl_xor(pc, off);
    }
    if (lane == 0) {
        a[node] = pa + beta[0];
        c[node] = pc + beta[1];
    }
}

// ---------------- out[i][j] = a[i] + c[j] (plain stores — R8-proven) ----------------
__global__ __launch_bounds__(256) void out_kernel(const float* __restrict__ a,
                                                  const float* __restrict__ c,
                                                  f32x4* __restrict__ out) {
    const f32x4* c4 = (const f32x4*)c;
    size_t base = (size_t)blockIdx.x * 1024 + threadIdx.x;
#pragma unroll
    for (int q = 0; q < 4; ++q) {
        size_t idx = base + q * 256;
        int i = (int)(idx >> 11);
        int j4 = (int)(idx & 2047);
        f32x4 r = c4[j4] + a[i];
        out[idx] = r;
    }
}

extern "C" void kernel_launch(void* const* d_in, const int* in_sizes, int n_in,
                              void* d_out, int out_size, void* d_ws, size_t ws_size,
                              hipStream_t stream) {
    const float* x    = (const float*)d_in[0];
    const int*   ei   = (const int*)d_in[1];
    const float* W1   = (const float*)d_in[2];
    const float* b1   = (const float*)d_in[3];
    const float* W2   = (const float*)d_in[4];
    const float* b2   = (const float*)d_in[5];
    const float* Wout = (const float*)d_in[6];
    const float* bout = (const float*)d_in[7];
    const float* We   = (const float*)d_in[8];
    const float* bedge= (const float*)d_in[9];
    const int* src = ei;
    const int* dst = ei + NE;

    // workspace
    int* cnt     = (int*)d_ws;                    // 8192
    int* bucket  = cnt + NN;                      // 8192*128
    float* u     = (float*)(bucket + NN * BCAP);  // 128
    float* v     = u + DIM;                       // 128
    float* beta  = v + DIM;                       // 2 (pad 16)
    float* g1    = beta + 16;                     // 8192*128
    float* s2    = g1 + NN * DIM;                 // 8192*128
    float* g2    = s2 + NN * DIM;                 // 8192*128
    float* av    = g2 + NN * DIM;                 // 8192
    float* cv    = av + NN;                       // 8192

    float* out = (float*)d_out;

    // ---- ATTRIBUTION ROUND #2 (R11 kernels, bit-identical):
    // {zero, fused_pre} x3 (pair idempotent) and out_kernel x4 (pure).
    // Delta vs 109.95 = 2*T_fpz + 3*T_out + ~8 gaps.
    zero_kernel<<<32, 256, 0, stream>>>(cnt);
    fused_pre<<<1281, 256, 0, stream>>>(x, W1, g1, src, dst, cnt, bucket,
                                        Wout, bout, We, bedge, u, v, beta);
    zero_kernel<<<32, 256, 0, stream>>>(cnt);
    fused_pre<<<1281, 256, 0, stream>>>(x, W1, g1, src, dst, cnt, bucket,
                                        Wout, bout, We, bedge, u, v, beta);
    zero_kernel<<<32, 256, 0, stream>>>(cnt);
    fused_pre<<<1281, 256, 0, stream>>>(x, W1, g1, src, dst, cnt, bucket,
                                        Wout, bout, We, bedge, u, v, beta);
    gather_scale<<<NN / 4, 256, 0, stream>>>(g1, cnt, bucket, b1, (f32x2*)s2);
    gemm_mid<<<NN / 32, 256, 0, stream>>>(s2, W2, g2);
    agg_head<<<NN / 4, 256, 0, stream>>>(g2, cnt, bucket, b2, u, v, beta, av, cv);
    out_kernel<<<(NN * NN / 4) / 1024, 256, 0, stream>>>(av, cv, (f32x4*)out);
    out_kernel<<<(NN * NN / 4) / 1024, 256, 0, stream>>>(av, cv, (f32x4*)out);
    out_kernel<<<(NN * NN / 4) / 1024, 256, 0, stream>>>(av, cv, (f32x4*)out);
    out_kernel<<<(NN * NN / 4) / 1024, 256, 0, stream>>>(av, cv, (f32x4*)out);
}

// Round 15
// 113.726 us; speedup vs baseline: 2.2873x; 2.2873x over previous
//
#include <hip/hip_runtime.h>

#define NN 8192      // nodes
#define NE 262144    // edges
#define DIM 128
#define BCAP 128     // bucket capacity (deg ~ Poisson(32); P(deg>128) ~ 0)

typedef float f32x4 __attribute__((ext_vector_type(4)));
typedef float f32x2 __attribute__((ext_vector_type(2)));

__device__ __forceinline__ float4 f4fma(float s, float4 w, float4 acc) {
    acc.x = fmaf(s, w.x, acc.x);
    acc.y = fmaf(s, w.y, acc.y);
    acc.z = fmaf(s, w.z, acc.z);
    acc.w = fmaf(s, w.w, acc.w);
    return acc;
}
__device__ __forceinline__ float f4dot(float4 a, float4 b) {
    return fmaf(a.x, b.x, fmaf(a.y, b.y, fmaf(a.z, b.z, a.w * b.w)));
}

// ---------------- K1: zero cnt ----------------
__global__ __launch_bounds__(256) void zero_kernel(int* __restrict__ cnt) {
    cnt[blockIdx.x * 256 + threadIdx.x] = 0;
}

// ---------------- K2: fused [gemm_pre_raw (blk 0-255)] | [scatter (blk 256-1279)] | [uv (blk 1280)] ----------------
__global__ __launch_bounds__(256) void fused_pre(const float* __restrict__ X,
                                                 const float* __restrict__ W,
                                                 float* __restrict__ G,
                                                 const int* __restrict__ src,
                                                 const int* __restrict__ dst,
                                                 int* __restrict__ cnt,
                                                 int* __restrict__ bucket,
                                                 const float* __restrict__ Wout,
                                                 const float* __restrict__ bout,
                                                 const float* __restrict__ we,
                                                 const float* __restrict__ bedge,
                                                 float* __restrict__ u,
                                                 float* __restrict__ v,
                                                 float* __restrict__ beta) {
    __shared__ float4 Wl[128 * 32];  // 64KB (gemm branch only)
    __shared__ float4 Xl[32 * 32];   // 16KB (gemm); overlaid as red[] by uv branch
    int tid = threadIdx.x;
    int bid = blockIdx.x;

    if (bid < 256) {
        // ---- raw GEMM: G1[r] = (x @ W1)[r] (dinv commuted into gather) ----
        int rbase = bid * 32;
        const float4* W4 = (const float4*)W;
#pragma unroll
        for (int i = 0; i < 16; ++i) Wl[i * 256 + tid] = W4[i * 256 + tid];
        const float4* X4 = (const float4*)(X + rbase * DIM);
#pragma unroll
        for (int i = 0; i < 4; ++i) Xl[i * 256 + tid] = X4[i * 256 + tid];
        __syncthreads();

        int tx = tid & 31;
        int ty = tid >> 5;
        float4 acc[4];
#pragma unroll
        for (int i = 0; i < 4; ++i) acc[i] = make_float4(0.f, 0.f, 0.f, 0.f);

        for (int k4 = 0; k4 < 32; ++k4) {
            float4 w0 = Wl[(k4 * 4 + 0) * 32 + tx];
            float4 w1 = Wl[(k4 * 4 + 1) * 32 + tx];
            float4 w2 = Wl[(k4 * 4 + 2) * 32 + tx];
            float4 w3 = Wl[(k4 * 4 + 3) * 32 + tx];
#pragma unroll
            for (int i = 0; i < 4; ++i) {
                float4 xv = Xl[(ty * 4 + i) * 32 + k4];
                acc[i] = f4fma(xv.x, w0, acc[i]);
                acc[i] = f4fma(xv.y, w1, acc[i]);
                acc[i] = f4fma(xv.z, w2, acc[i]);
                acc[i] = f4fma(xv.w, w3, acc[i]);
            }
        }
        float4* G4 = (float4*)G;
#pragma unroll
        for (int i = 0; i < 4; ++i) {
            int r = rbase + ty * 4 + i;
            G4[r * 32 + tx] = acc[i];   // plain store: table stays cacheable
        }
        return;
    }
    if (bid < 1280) {
        // ---- scatter edges into buckets; cnt ends as indegree ----
        int e = (bid - 256) * 256 + tid;
        int d = dst[e];
        int p = atomicAdd(&cnt[d], 1);
        if (p < BCAP) bucket[(d << 7) + p] = src[e];
        return;
    }
    // ---- block 1280: u/v/beta ----
    float* red = (float*)Xl;
    int k = tid;
    if (k < DIM) {
        const float4* W4o = (const float4*)(Wout + (k << 7));
        const float4* we4 = (const float4*)we;
        float su = 0.f, sv = 0.f;
#pragma unroll
        for (int j = 0; j < 32; ++j) {
            float4 w = W4o[j];
            su += f4dot(w, we4[j]);
            sv += f4dot(w, we4[32 + j]);
        }
        u[k] = su;
        v[k] = sv;
    }
    red[k] = (k < DIM) ? bout[k] * we[k] : 0.f;
    __syncthreads();
    for (int off = 128; off >= 1; off >>= 1) {
        if (k < off) red[k] += red[k + off];
        __syncthreads();
    }
    float b0 = red[0];
    __syncthreads();
    red[k] = (k < DIM) ? bout[k] * we[DIM + k] : 0.f;
    __syncthreads();
    for (int off = 128; off >= 1; off >>= 1) {
        if (k < off) red[k] += red[k + off];
        __syncthreads();
    }
    if (k == 0) {
        beta[0] = b0 + bedge[0];
        beta[1] = red[0];
    }
}

// ---------------- F2: fused gather(G1, weight-shuffle) + S2 in LDS + GEMM(W2) -> G2 raw ----------------
// 4 waves x 8 nodes = 32 rows (R6-verified mapping). Per-lane weights computed once,
// shuffled per edge (bit-identical to per-edge recompute).
__global__ __launch_bounds__(256) void gather_gemm(const float* __restrict__ G1,
                                                   const int* __restrict__ cnt,
                                                   const int* __restrict__ bucket,
                                                   const float* __restrict__ b1,
                                                   const float* __restrict__ W2,
                                                   float* __restrict__ G2) {
    __shared__ float4 Wl[128 * 32];  // 64KB
    __shared__ float4 Xl[32 * 32];   // 16KB
    int tid = threadIdx.x;
    int rbase = blockIdx.x * 32;
    int w = tid >> 6;
    int lane = tid & 63;
    const float2* G12 = (const float2*)G1;

    int deg[8], i0[8], i1[8];
    float dv[8], w0[8], w1[8];
    float2 acc[8];
    int nb = rbase + w * 8;
#pragma unroll
    for (int j = 0; j < 8; ++j) {
        int n = nb + j;
        int degree = cnt[n];
        dv[j] = rsqrtf((float)(degree + 1));
        deg[j] = min(degree, BCAP);
        int a0 = __builtin_nontemporal_load(bucket + (n << 7) + lane);
        int a1 = __builtin_nontemporal_load(bucket + (n << 7) + 64 + lane);
        i0[j] = (lane < deg[j]) ? a0 : 0;        // sanitize poison tail
        i1[j] = (64 + lane < deg[j]) ? a1 : 0;
        acc[j] = G12[n * 64 + lane];             // self term
        acc[j].x *= dv[j];
        acc[j].y *= dv[j];
    }
#pragma unroll
    for (int j = 0; j < 8; ++j) {
        w0[j] = rsqrtf((float)(cnt[i0[j]] + 1));  // per-lane weight, computed once
        w1[j] = rsqrtf((float)(cnt[i1[j]] + 1));
    }

    // W2 -> LDS (overlaps with gather latency)
    const float4* W4 = (const float4*)W2;
#pragma unroll
    for (int i = 0; i < 16; ++i) Wl[i * 256 + tid] = W4[i * 256 + tid];

    int m = max(max(max(deg[0], deg[1]), max(deg[2], deg[3])),
                max(max(deg[4], deg[5]), max(deg[6], deg[7])));
    for (int e = 0; e < m; ++e) {
        int lo = e & 63;
        bool hi = e >= 64;
#pragma unroll
        for (int j = 0; j < 8; ++j) {
            int s = __shfl(hi ? i1[j] : i0[j], lo);
            float wt = __shfl(hi ? w1[j] : w0[j], lo);
            bool val = e < deg[j];
            wt = val ? wt : 0.f;                 // s already safe (0 when invalid)
            float2 t = G12[s * 64 + lane];
            acc[j].x = fmaf(t.x, wt, acc[j].x);
            acc[j].y = fmaf(t.y, wt, acc[j].y);
        }
    }

    // S2 = dv * relu(dv*y + b1) -> Xl rows w*8..w*8+7
    const float2* B2 = (const float2*)b1;
    float2 bb = B2[lane];
    float2* Xl2 = (float2*)Xl;
#pragma unroll
    for (int j = 0; j < 8; ++j) {
        float2 o;
        o.x = fmaxf(fmaf(acc[j].x, dv[j], bb.x), 0.f) * dv[j];
        o.y = fmaxf(fmaf(acc[j].y, dv[j], bb.y), 0.f) * dv[j];
        Xl2[(w * 8 + j) * 64 + lane] = o;
    }
    __syncthreads();

    // GEMM: G2 = S2 @ W2 (raw, plain store)
    int tx = tid & 31;
    int ty = tid >> 5;
    float4 accg[4];
#pragma unroll
    for (int i = 0; i < 4; ++i) accg[i] = make_float4(0.f, 0.f, 0.f, 0.f);

    for (int k4 = 0; k4 < 32; ++k4) {
        float4 q0 = Wl[(k4 * 4 + 0) * 32 + tx];
        float4 q1 = Wl[(k4 * 4 + 1) * 32 + tx];
        float4 q2 = Wl[(k4 * 4 + 2) * 32 + tx];
        float4 q3 = Wl[(k4 * 4 + 3) * 32 + tx];
#pragma unroll
        for (int i = 0; i < 4; ++i) {
            float4 xv = Xl[(ty * 4 + i) * 32 + k4];
            accg[i] = f4fma(xv.x, q0, accg[i]);
            accg[i] = f4fma(xv.y, q1, accg[i]);
            accg[i] = f4fma(xv.z, q2, accg[i]);
            accg[i] = f4fma(xv.w, q3, accg[i]);
        }
    }

    float4* G4 = (float4*)G2;
#pragma unroll
    for (int i = 0; i < 4; ++i) {
        int r = rbase + ty * 4 + i;
        G4[r * 32 + tx] = accg[i];
    }
}

// ---------------- F4: gather(G2) + head -> a, c (ILP-8) ----------------
__global__ __launch_bounds__(256) void agg_head(const float* __restrict__ G2,
                                                const int* __restrict__ cnt,
                                                const int* __restrict__ bucket,
                                                const float* __restrict__ b2,
                                                const float* __restrict__ u,
                                                const float* __restrict__ v,
                                                const float* __restrict__ beta,
                                                float* __restrict__ a,
                                                float* __restrict__ c) {
    int node = blockIdx.x * 4 + (threadIdx.x >> 6);
    int lane = threadIdx.x & 63;
    const float2* G22 = (const float2*)G2;

    int degree = cnt[node];
    float dv = rsqrtf((float)(degree + 1));
    int deg = min(degree, BCAP);
    int i0 = __builtin_nontemporal_load(bucket + (node << 7) + lane);
    int i1 = __builtin_nontemporal_load(bucket + (node << 7) + 64 + lane);

    float2 selfv = G22[node * 64 + lane];
    float ax = selfv.x, ay = selfv.y;
    float px[8], py[8];
#pragma unroll
    for (int k = 0; k < 8; ++k) { px[k] = 0.f; py[k] = 0.f; }

    int d8 = deg & ~7;
    for (int e = 0; e < d8; e += 8) {
        int s[8];
#pragma unroll
        for (int k = 0; k < 8; ++k) s[k] = __shfl((e + k) >= 64 ? i1 : i0, (e + k) & 63);
#pragma unroll
        for (int k = 0; k < 8; ++k) {
            float2 t = G22[s[k] * 64 + lane];
            px[k] += t.x;
            py[k] += t.y;
        }
    }
    for (int e = d8; e < deg; ++e) {
        int s = __shfl(e >= 64 ? i1 : i0, e & 63);
        float2 t = G22[s * 64 + lane];
        ax += t.x;
        ay += t.y;
    }
    float yx = ax + ((px[0] + px[1]) + (px[2] + px[3])) + ((px[4] + px[5]) + (px[6] + px[7]));
    float yy = ay + ((py[0] + py[1]) + (py[2] + py[3])) + ((py[4] + py[5]) + (py[6] + py[7]));

    const float2* B2 = (const float2*)b2;
    float2 bb = B2[lane];
    float h0 = fmaxf(fmaf(yx, dv, bb.x), 0.f);
    float h1 = fmaxf(fmaf(yy, dv, bb.y), 0.f);

    float2 uu = ((const float2*)u)[lane];
    float2 vv = ((const float2*)v)[lane];
    float pa = h0 * uu.x + h1 * uu.y;
    float pc = h0 * vv.x + h1 * vv.y;
#pragma unroll
    for (int off = 32; off >= 1; off >>= 1) {
        pa += __shfl_xor(pa, off);
        pc += __shfl_xor(pc, off);
    }
    if (lane == 0) {
        a[node] = pa + beta[0];
        c[node] = pc + beta[1];
    }
}

// ---------------- out[i][j] = a[i] + c[j] (plain stores — R8-proven) ----------------
__global__ __launch_bounds__(256) void out_kernel(const float* __restrict__ a,
                                                  const float* __restrict__ c,
                                                  f32x4* __restrict__ out) {
    const f32x4* c4 = (const f32x4*)c;
    size_t base = (size_t)blockIdx.x * 1024 + threadIdx.x;
#pragma unroll
    for (int q = 0; q < 4; ++q) {
        size_t idx = base + q * 256;
        int i = (int)(idx >> 11);
        int j4 = (int)(idx & 2047);
        f32x4 r = c4[j4] + a[i];
        out[idx] = r;
    }
}

extern "C" void kernel_launch(void* const* d_in, const int* in_sizes, int n_in,
                              void* d_out, int out_size, void* d_ws, size_t ws_size,
                              hipStream_t stream) {
    const float* x    = (const float*)d_in[0];
    const int*   ei   = (const int*)d_in[1];
    const float* W1   = (const float*)d_in[2];
    const float* b1   = (const float*)d_in[3];
    const float* W2   = (const float*)d_in[4];
    const float* b2   = (const float*)d_in[5];
    const float* Wout = (const float*)d_in[6];
    const float* bout = (const float*)d_in[7];
    const float* We   = (const float*)d_in[8];
    const float* bedge= (const float*)d_in[9];
    const int* src = ei;
    const int* dst = ei + NE;

    // workspace
    int* cnt     = (int*)d_ws;                    // 8192
    int* bucket  = cnt + NN;                      // 8192*128
    float* u     = (float*)(bucket + NN * BCAP);  // 128
    float* v     = u + DIM;                       // 128
    float* beta  = v + DIM;                       // 2 (pad 16)
    float* g1    = beta + 16;                     // 8192*128
    float* g2    = g1 + NN * DIM;                 // 8192*128
    float* av    = g2 + NN * DIM;                 // 8192
    float* cv    = av + NN;                       // 8192

    float* out = (float*)d_out;

    zero_kernel<<<32, 256, 0, stream>>>(cnt);
    fused_pre<<<1281, 256, 0, stream>>>(x, W1, g1, src, dst, cnt, bucket,
                                        Wout, bout, We, bedge, u, v, beta);
    gather_gemm<<<NN / 32, 256, 0, stream>>>(g1, cnt, bucket, b1, W2, g2);
    agg_head<<<NN / 4, 256, 0, stream>>>(g2, cnt, bucket, b2, u, v, beta, av, cv);
    out_kernel<<<(NN * NN / 4) / 1024, 256, 0, stream>>>(av, cv, (f32x4*)out);
}

// Round 16
// 101.901 us; speedup vs baseline: 2.5528x; 1.1160x over previous
//
#include <hip/hip_runtime.h>

#define NN 8192      // nodes
#define NE 262144    // edges
#define DIM 128
#define BCAP 128     // bucket capacity (deg ~ Poisson(32); P(deg>128) ~ 0)

typedef float f32x4 __attribute__((ext_vector_type(4)));
typedef float f32x2 __attribute__((ext_vector_type(2)));

__device__ __forceinline__ float4 f4fma(float s, float4 w, float4 acc) {
    acc.x = fmaf(s, w.x, acc.x);
    acc.y = fmaf(s, w.y, acc.y);
    acc.z = fmaf(s, w.z, acc.z);
    acc.w = fmaf(s, w.w, acc.w);
    return acc;
}
__device__ __forceinline__ float f4dot(float4 a, float4 b) {
    return fmaf(a.x, b.x, fmaf(a.y, b.y, fmaf(a.z, b.z, a.w * b.w)));
}
__device__ __forceinline__ f32x4 vfma(f32x4 t, float w, f32x4 acc) {
    acc.x = fmaf(t.x, w, acc.x);
    acc.y = fmaf(t.y, w, acc.y);
    acc.z = fmaf(t.z, w, acc.z);
    acc.w = fmaf(t.w, w, acc.w);
    return acc;
}

// ---------------- K1: zero cnt ----------------
__global__ __launch_bounds__(256) void zero_kernel(int* __restrict__ cnt) {
    cnt[blockIdx.x * 256 + threadIdx.x] = 0;
}

// ---------------- K2: fused [gemm_pre_raw (blk 0-255)] | [scatter (blk 256-1279)] | [uv (blk 1280)] ----------------
__global__ __launch_bounds__(256) void fused_pre(const float* __restrict__ X,
                                                 const float* __restrict__ W,
                                                 float* __restrict__ G,
                                                 const int* __restrict__ src,
                                                 const int* __restrict__ dst,
                                                 int* __restrict__ cnt,
                                                 int* __restrict__ bucket,
                                                 const float* __restrict__ Wout,
                                                 const float* __restrict__ bout,
                                                 const float* __restrict__ we,
                                                 const float* __restrict__ bedge,
                                                 float* __restrict__ u,
                                                 float* __restrict__ v,
                                                 float* __restrict__ beta) {
    __shared__ float4 Wl[128 * 32];  // 64KB (gemm branch only)
    __shared__ float4 Xl[32 * 32];   // 16KB (gemm); overlaid as red[] by uv branch
    int tid = threadIdx.x;
    int bid = blockIdx.x;

    if (bid < 256) {
        // ---- raw GEMM: G1[r] = (x @ W1)[r] (dinv commuted into gather) ----
        int rbase = bid * 32;
        const float4* W4 = (const float4*)W;
#pragma unroll
        for (int i = 0; i < 16; ++i) Wl[i * 256 + tid] = W4[i * 256 + tid];
        const float4* X4 = (const float4*)(X + rbase * DIM);
#pragma unroll
        for (int i = 0; i < 4; ++i) Xl[i * 256 + tid] = X4[i * 256 + tid];
        __syncthreads();

        int tx = tid & 31;
        int ty = tid >> 5;
        float4 acc[4];
#pragma unroll
        for (int i = 0; i < 4; ++i) acc[i] = make_float4(0.f, 0.f, 0.f, 0.f);

        for (int k4 = 0; k4 < 32; ++k4) {
            float4 w0 = Wl[(k4 * 4 + 0) * 32 + tx];
            float4 w1 = Wl[(k4 * 4 + 1) * 32 + tx];
            float4 w2 = Wl[(k4 * 4 + 2) * 32 + tx];
            float4 w3 = Wl[(k4 * 4 + 3) * 32 + tx];
#pragma unroll
            for (int i = 0; i < 4; ++i) {
                float4 xv = Xl[(ty * 4 + i) * 32 + k4];
                acc[i] = f4fma(xv.x, w0, acc[i]);
                acc[i] = f4fma(xv.y, w1, acc[i]);
                acc[i] = f4fma(xv.z, w2, acc[i]);
                acc[i] = f4fma(xv.w, w3, acc[i]);
            }
        }
        float4* G4 = (float4*)G;
#pragma unroll
        for (int i = 0; i < 4; ++i) {
            int r = rbase + ty * 4 + i;
            G4[r * 32 + tx] = acc[i];   // plain store: table stays cacheable
        }
        return;
    }
    if (bid < 1280) {
        // ---- scatter edges into buckets; cnt ends as indegree ----
        int e = (bid - 256) * 256 + tid;
        int d = dst[e];
        int p = atomicAdd(&cnt[d], 1);
        if (p < BCAP) bucket[(d << 7) + p] = src[e];
        return;
    }
    // ---- block 1280: u/v/beta ----
    float* red = (float*)Xl;
    int k = tid;
    if (k < DIM) {
        const float4* W4o = (const float4*)(Wout + (k << 7));
        const float4* we4 = (const float4*)we;
        float su = 0.f, sv = 0.f;
#pragma unroll
        for (int j = 0; j < 32; ++j) {
            float4 w = W4o[j];
            su += f4dot(w, we4[j]);
            sv += f4dot(w, we4[32 + j]);
        }
        u[k] = su;
        v[k] = sv;
    }
    red[k] = (k < DIM) ? bout[k] * we[k] : 0.f;
    __syncthreads();
    for (int off = 128; off >= 1; off >>= 1) {
        if (k < off) red[k] += red[k + off];
        __syncthreads();
    }
    float b0 = red[0];
    __syncthreads();
    red[k] = (k < DIM) ? bout[k] * we[DIM + k] : 0.f;
    __syncthreads();
    for (int off = 128; off >= 1; off >>= 1) {
        if (k < off) red[k] += red[k + off];
        __syncthreads();
    }
    if (k == 0) {
        beta[0] = b0 + bedge[0];
        beta[1] = red[0];
    }
}

// ---------------- F2: half-wave float4 gather(G1) + S2 = dv*relu(dv*y + b1) ----------------
// One wave per node. half = lane>>5 processes alternate edges; lane holds 4 features.
// One load instruction = 2 rows (2 edges). Weights computed once per slot, shfl'd.
__global__ __launch_bounds__(256) void gather_scale(const float* __restrict__ G1,
                                                    const int* __restrict__ cnt,
                                                    const int* __restrict__ bucket,
                                                    const float* __restrict__ b1,
                                                    float* __restrict__ S2) {
    int node = blockIdx.x * 4 + (threadIdx.x >> 6);
    int lane = threadIdx.x & 63;
    int half = lane >> 5;
    int fl = lane & 31;
    const f32x4* G14 = (const f32x4*)G1;

    int degree = cnt[node];
    float dv = rsqrtf((float)(degree + 1));
    int deg = min(degree, BCAP);
    int a0 = __builtin_nontemporal_load(bucket + (node << 7) + lane);
    int a1 = __builtin_nontemporal_load(bucket + (node << 7) + 64 + lane);
    int i0s = (lane < deg) ? a0 : 0;          // sanitize poison tail
    int i1s = (64 + lane < deg) ? a1 : 0;
    float w0 = (lane < deg) ? rsqrtf((float)(cnt[i0s] + 1)) : 0.f;
    float w1 = (64 + lane < deg) ? rsqrtf((float)(cnt[i1s] + 1)) : 0.f;

    f32x4 zero4 = {0.f, 0.f, 0.f, 0.f};
    f32x4 p0 = zero4, p1 = zero4, p2 = zero4, p3 = zero4;
    f32x4 self4 = G14[node * 32 + fl];
    f32x4 acc = zero4;
    if (half == 0) {  // self term counted once
        acc.x = self4.x * dv; acc.y = self4.y * dv;
        acc.z = self4.z * dv; acc.w = self4.w * dv;
    }

    int L1 = min(deg, 64);
    int E1 = (L1 + 7) & ~7;           // zero-weight tail slots make padding safe
    for (int e = 0; e < E1; e += 8) {
        int q = e + half;
        int s0 = __shfl(i0s, q);     float q0w = __shfl(w0, q);
        int s1 = __shfl(i0s, q + 2); float q1w = __shfl(w0, q + 2);
        int s2 = __shfl(i0s, q + 4); float q2w = __shfl(w0, q + 4);
        int s3 = __shfl(i0s, q + 6); float q3w = __shfl(w0, q + 6);
        f32x4 t0 = G14[s0 * 32 + fl];
        f32x4 t1 = G14[s1 * 32 + fl];
        f32x4 t2 = G14[s2 * 32 + fl];
        f32x4 t3 = G14[s3 * 32 + fl];
        p0 = vfma(t0, q0w, p0);
        p1 = vfma(t1, q1w, p1);
        p2 = vfma(t2, q2w, p2);
        p3 = vfma(t3, q3w, p3);
    }
    if (deg > 64) {
        int L2 = deg - 64;
        int E2 = (L2 + 7) & ~7;
        for (int e = 0; e < E2; e += 8) {
            int q = e + half;
            int s0 = __shfl(i1s, q);     float q0w = __shfl(w1, q);
            int s1 = __shfl(i1s, q + 2); float q1w = __shfl(w1, q + 2);
            int s2 = __shfl(i1s, q + 4); float q2w = __shfl(w1, q + 4);
            int s3 = __shfl(i1s, q + 6); float q3w = __shfl(w1, q + 6);
            f32x4 t0 = G14[s0 * 32 + fl];
            f32x4 t1 = G14[s1 * 32 + fl];
            f32x4 t2 = G14[s2 * 32 + fl];
            f32x4 t3 = G14[s3 * 32 + fl];
            p0 = vfma(t0, q0w, p0);
            p1 = vfma(t1, q1w, p1);
            p2 = vfma(t2, q2w, p2);
            p3 = vfma(t3, q3w, p3);
        }
    }

    f32x4 sum = ((p0 + p1) + (p2 + p3)) + acc;
    f32x4 oth;
    oth.x = __shfl_xor(sum.x, 32);
    oth.y = __shfl_xor(sum.y, 32);
    oth.z = __shfl_xor(sum.z, 32);
    oth.w = __shfl_xor(sum.w, 32);
    sum += oth;

    f32x4 bb = ((const f32x4*)b1)[fl];
    f32x4 o;
    o.x = fmaxf(fmaf(sum.x, dv, bb.x), 0.f) * dv;
    o.y = fmaxf(fmaf(sum.y, dv, bb.y), 0.f) * dv;
    o.z = fmaxf(fmaf(sum.z, dv, bb.z), 0.f) * dv;
    o.w = fmaxf(fmaf(sum.w, dv, bb.w), 0.f) * dv;
    if (half == 0) ((f32x4*)S2)[node * 32 + fl] = o;
}

// ---------------- F3: G2 = S2 @ W2 (raw), plain store ----------------
__global__ __launch_bounds__(256) void gemm_mid(const float* __restrict__ X,
                                                const float* __restrict__ W,
                                                float* __restrict__ G) {
    __shared__ float4 Wl[128 * 32];
    __shared__ float4 Xl[32 * 32];
    int tid = threadIdx.x;
    int rbase = blockIdx.x * 32;

    const float4* W4 = (const float4*)W;
#pragma unroll
    for (int i = 0; i < 16; ++i) Wl[i * 256 + tid] = W4[i * 256 + tid];
    const float4* X4 = (const float4*)(X + rbase * DIM);
#pragma unroll
    for (int i = 0; i < 4; ++i) Xl[i * 256 + tid] = X4[i * 256 + tid];
    __syncthreads();

    int tx = tid & 31;
    int ty = tid >> 5;
    float4 acc[4];
#pragma unroll
    for (int i = 0; i < 4; ++i) acc[i] = make_float4(0.f, 0.f, 0.f, 0.f);

    for (int k4 = 0; k4 < 32; ++k4) {
        float4 w0 = Wl[(k4 * 4 + 0) * 32 + tx];
        float4 w1 = Wl[(k4 * 4 + 1) * 32 + tx];
        float4 w2 = Wl[(k4 * 4 + 2) * 32 + tx];
        float4 w3 = Wl[(k4 * 4 + 3) * 32 + tx];
#pragma unroll
        for (int i = 0; i < 4; ++i) {
            float4 xv = Xl[(ty * 4 + i) * 32 + k4];
            acc[i] = f4fma(xv.x, w0, acc[i]);
            acc[i] = f4fma(xv.y, w1, acc[i]);
            acc[i] = f4fma(xv.z, w2, acc[i]);
            acc[i] = f4fma(xv.w, w3, acc[i]);
        }
    }

    float4* G4 = (float4*)G;
#pragma unroll
    for (int i = 0; i < 4; ++i) {
        int r = rbase + ty * 4 + i;
        G4[r * 32 + tx] = acc[i];
    }
}

// ---------------- F4: half-wave float4 gather(G2) + head -> a, c ----------------
__global__ __launch_bounds__(256) void agg_head(const float* __restrict__ G2,
                                                const int* __restrict__ cnt,
                                                const int* __restrict__ bucket,
                                                const float* __restrict__ b2,
                                                const float* __restrict__ u,
                                                const float* __restrict__ v,
                                                const float* __restrict__ beta,
                                                float* __restrict__ a,
                                                float* __restrict__ c) {
    int node = blockIdx.x * 4 + (threadIdx.x >> 6);
    int lane = threadIdx.x & 63;
    int half = lane >> 5;
    int fl = lane & 31;
    const f32x4* G24 = (const f32x4*)G2;

    int degree = cnt[node];
    float dv = rsqrtf((float)(degree + 1));
    int deg = min(degree, BCAP);
    int a0 = __builtin_nontemporal_load(bucket + (node << 7) + lane);
    int a1 = __builtin_nontemporal_load(bucket + (node << 7) + 64 + lane);
    int i0s = (lane < deg) ? a0 : 0;
    int i1s = (64 + lane < deg) ? a1 : 0;

    f32x4 zero4 = {0.f, 0.f, 0.f, 0.f};
    f32x4 p0 = zero4, p1 = zero4, p2 = zero4, p3 = zero4;
    f32x4 acc = (half == 0) ? G24[node * 32 + fl] : zero4;  // self, weight 1, once

    int L1 = min(deg, 64);
    int E1 = (L1 + 7) & ~7;
    for (int e = 0; e < E1; e += 8) {
        int q = e + half;
        int s0 = __shfl(i0s, q);
        int s1 = __shfl(i0s, q + 2);
        int s2 = __shfl(i0s, q + 4);
        int s3 = __shfl(i0s, q + 6);
        float q0w = (q < L1) ? 1.f : 0.f;        // local validity (uniform weight)
        float q1w = (q + 2 < L1) ? 1.f : 0.f;
        float q2w = (q + 4 < L1) ? 1.f : 0.f;
        float q3w = (q + 6 < L1) ? 1.f : 0.f;
        f32x4 t0 = G24[s0 * 32 + fl];
        f32x4 t1 = G24[s1 * 32 + fl];
        f32x4 t2 = G24[s2 * 32 + fl];
        f32x4 t3 = G24[s3 * 32 + fl];
        p0 = vfma(t0, q0w, p0);
        p1 = vfma(t1, q1w, p1);
        p2 = vfma(t2, q2w, p2);
        p3 = vfma(t3, q3w, p3);
    }
    if (deg > 64) {
        int L2 = deg - 64;
        int E2 = (L2 + 7) & ~7;
        for (int e = 0; e < E2; e += 8) {
            int q = e + half;
            int s0 = __shfl(i1s, q);
            int s1 = __shfl(i1s, q + 2);
            int s2 = __shfl(i1s, q + 4);
            int s3 = __shfl(i1s, q + 6);
            float q0w = (q < L2) ? 1.f : 0.f;
            float q1w = (q + 2 < L2) ? 1.f : 0.f;
            float q2w = (q + 4 < L2) ? 1.f : 0.f;
            float q3w = (q + 6 < L2) ? 1.f : 0.f;
            f32x4 t0 = G24[s0 * 32 + fl];
            f32x4 t1 = G24[s1 * 32 + fl];
            f32x4 t2 = G24[s2 * 32 + fl];
            f32x4 t3 = G24[s3 * 32 + fl];
            p0 = vfma(t0, q0w, p0);
            p1 = vfma(t1, q1w, p1);
            p2 = vfma(t2, q2w, p2);
            p3 = vfma(t3, q3w, p3);
        }
    }

    f32x4 sum = ((p0 + p1) + (p2 + p3)) + acc;
    f32x4 oth;
    oth.x = __shfl_xor(sum.x, 32);
    oth.y = __shfl_xor(sum.y, 32);
    oth.z = __shfl_xor(sum.z, 32);
    oth.w = __shfl_xor(sum.w, 32);
    sum += oth;

    f32x4 bb = ((const f32x4*)b2)[fl];
    f32x4 h;
    h.x = fmaxf(fmaf(sum.x, dv, bb.x), 0.f);
    h.y = fmaxf(fmaf(sum.y, dv, bb.y), 0.f);
    h.z = fmaxf(fmaf(sum.z, dv, bb.z), 0.f);
    h.w = fmaxf(fmaf(sum.w, dv, bb.w), 0.f);

    f32x4 uu = ((const f32x4*)u)[fl];
    f32x4 vv = ((const f32x4*)v)[fl];
    float pa = fmaf(h.x, uu.x, fmaf(h.y, uu.y, fmaf(h.z, uu.z, h.w * uu.w)));
    float pc = fmaf(h.x, vv.x, fmaf(h.y, vv.y, fmaf(h.z, vv.z, h.w * vv.w)));
#pragma unroll
    for (int off = 16; off >= 1; off >>= 1) {   // butterfly within each 32-half
        pa += __shfl_xor(pa, off);
        pc += __shfl_xor(pc, off);
    }
    if (lane == 0) {
        a[node] = pa + beta[0];
        c[node] = pc + beta[1];
    }
}

// ---------------- out[i][j] = a[i] + c[j] (plain stores — R8-proven) ----------------
__global__ __launch_bounds__(256) void out_kernel(const float* __restrict__ a,
                                                  const float* __restrict__ c,
                                                  f32x4* __restrict__ out) {
    const f32x4* c4 = (const f32x4*)c;
    size_t base = (size_t)blockIdx.x * 1024 + threadIdx.x;
#pragma unroll
    for (int q = 0; q < 4; ++q) {
        size_t idx = base + q * 256;
        int i = (int)(idx >> 11);
        int j4 = (int)(idx & 2047);
        f32x4 r = c4[j4] + a[i];
        out[idx] = r;
    }
}

extern "C" void kernel_launch(void* const* d_in, const int* in_sizes, int n_in,
                              void* d_out, int out_size, void* d_ws, size_t ws_size,
                              hipStream_t stream) {
    const float* x    = (const float*)d_in[0];
    const int*   ei   = (const int*)d_in[1];
    const float* W1   = (const float*)d_in[2];
    const float* b1   = (const float*)d_in[3];
    const float* W2   = (const float*)d_in[4];
    const float* b2   = (const float*)d_in[5];
    const float* Wout = (const float*)d_in[6];
    const float* bout = (const float*)d_in[7];
    const float* We   = (const float*)d_in[8];
    const float* bedge= (const float*)d_in[9];
    const int* src = ei;
    const int* dst = ei + NE;

    // workspace
    int* cnt     = (int*)d_ws;                    // 8192
    int* bucket  = cnt + NN;                      // 8192*128
    float* u     = (float*)(bucket + NN * BCAP);  // 128
    float* v     = u + DIM;                       // 128
    float* beta  = v + DIM;                       // 2 (pad 16)
    float* g1    = beta + 16;                     // 8192*128
    float* s2    = g1 + NN * DIM;                 // 8192*128
    float* g2    = s2 + NN * DIM;                 // 8192*128
    float* av    = g2 + NN * DIM;                 // 8192
    float* cv    = av + NN;                       // 8192

    float* out = (float*)d_out;

    zero_kernel<<<32, 256, 0, stream>>>(cnt);
    fused_pre<<<1281, 256, 0, stream>>>(x, W1, g1, src, dst, cnt, bucket,
                                        Wout, bout, We, bedge, u, v, beta);
    gather_scale<<<NN / 4, 256, 0, stream>>>(g1, cnt, bucket, b1, s2);
    gemm_mid<<<NN / 32, 256, 0, stream>>>(s2, W2, g2);
    agg_head<<<NN / 4, 256, 0, stream>>>(g2, cnt, bucket, b2, u, v, beta, av, cv);
    out_kernel<<<(NN * NN / 4) / 1024, 256, 0, stream>>>(av, cv, (f32x4*)out);
}